// Round 3
// baseline (221.553 us; speedup 1.0000x reference)
//
#include <hip/hip_runtime.h>
#include <math.h>

#define NN   1000
#define DD   128
#define CTXN 130
#define NEG_BIG (-1.0e30f)

// ============================================================================
// Multi-kernel pipeline: 4 streaming passes over emb, each with B*8 = 2048
// blocks (8 blocks/CU queued) instead of the fused kernel's 256 (1/CU).
// ws layout (floats): meanp[B][8][128] | qpt[B][8][128] | compat[B][8][1024]
//                     | wembp[B][8][1024] | logits[B][1024] | mflag(int)
// ============================================================================

// ---------------- K1: per-(b,s) partial sums for the graph mean ----------------
__global__ __launch_bounds__(256, 8)
void k1_meanpart(const float* __restrict__ emb, float* __restrict__ meanp) {
    const int b = blockIdx.x >> 3, s = blockIdx.x & 7;
    const int t = threadIdx.x;
    const float* eb = emb + (size_t)b * (NN * DD);
    __shared__ __align__(16) float s_red[8 * 128];
    const int c4 = t & 31, rg = t >> 5;
    float4 a = make_float4(0.f, 0.f, 0.f, 0.f);
    for (int nl = rg; nl < 125; nl += 8) {
        const float4 v = *(const float4*)(eb + (size_t)(s * 125 + nl) * DD + c4 * 4);
        a.x += v.x; a.y += v.y; a.z += v.z; a.w += v.w;
    }
    ((float4*)s_red)[rg * 32 + c4] = a;
    __syncthreads();
    if (t < 128) {
        float v = 0.f;
        #pragma unroll
        for (int g = 0; g < 8; ++g) v += s_red[g * 128 + t];
        meanp[(size_t)b * 1024 + s * 128 + t] = v;
    }
}

// ---------------- K1b: mean -> query -> qproj (transposed [h][i]), + mask probe ----------------
__global__ __launch_bounds__(512, 4)
void k1b_qproj(const float* __restrict__ meanp, const float* __restrict__ stepc,
               const void* __restrict__ maskp,
               const float* __restrict__ Wn, const float* __restrict__ Wf,
               const float* __restrict__ Ws,
               float* __restrict__ qpt, int* __restrict__ mflag) {
    const int b = blockIdx.x, t = threadIdx.x;
    __shared__ float s_mean[128], s_q[128];
    __shared__ float s_red[512];
    // probe mask element layout once (int32: bytes at 1 mod 4 are all zero)
    if (b == 0 && t == 0) {
        const unsigned char* mb8 = (const unsigned char*)maskp;
        int any = 0;
        for (int k = 0; k < 64; ++k) any |= mb8[4 * k + 1];
        *mflag = (any == 0) ? 1 : 0;
    }
    if (t < 128) {
        float v = 0.f;
        #pragma unroll
        for (int g = 0; g < 8; ++g) v += meanp[(size_t)b * 1024 + g * 128 + t];
        s_mean[t] = v * (1.0f / (float)NN);
    }
    __syncthreads();
    {   // query[d] = sum_i mean[i] Wf[i,d] + sum_c sc[c] Ws[c,d]
        const int d = t & 127, p = t >> 7;
        float a = 0.f;
        for (int i = 32 * p; i < 32 * p + 32; ++i)
            a = fmaf(s_mean[i], Wf[i * DD + d], a);
        const float* scb = stepc + (size_t)b * CTXN;
        const int c0 = 32 * p, c1 = (p == 3) ? CTXN : 32 * p + 32;
        for (int c = c0; c < c1; ++c)
            a = fmaf(scb[c], Ws[c * DD + d], a);
        s_red[p * 128 + d] = a;
    }
    __syncthreads();
    if (t < 128) s_q[t] = s_red[t] + s_red[128 + t] + s_red[256 + t] + s_red[384 + t];
    __syncthreads();
    {   // qpt[b][h][i] = 0.25 * sum_j Wn[i, 16h+j] q[16h+j]
        const int i = t & 127, p = t >> 7;
        #pragma unroll
        for (int u = 0; u < 2; ++u) {
            const int h = p + 4 * u;
            float a = 0.f;
            #pragma unroll
            for (int j = 0; j < 16; ++j)
                a = fmaf(Wn[i * 384 + h * 16 + j], s_q[h * 16 + j], a);
            qpt[(size_t)b * 1024 + h * 128 + i] = a * 0.25f;
        }
    }
}

// ---------------- K2: compat[b][h][n] = emb_n . qproj[:,h], masked ----------------
// 1024 thr = 16 waves: wave = (colslice cs = w>>1 [16 cols], head-half hb = (w&1)*4).
// qp tile per lane = 16 cols x 4 heads = 64 VGPR -> fits 4 waves/SIMD.
__global__ __launch_bounds__(1024, 4)
void k2_compat(const float* __restrict__ emb, const float* __restrict__ qpt,
               const void* __restrict__ maskp, const int* __restrict__ mflag,
               float* __restrict__ compat) {
    const int b = blockIdx.x >> 3, s = blockIdx.x & 7;
    const int t = threadIdx.x, w = t >> 6, lane = t & 63;
    const int cs = w >> 1, hb = (w & 1) * 4;
    const float* eb = emb + (size_t)b * (NN * DD);
    __shared__ __align__(16) float s_qpT[1024];
    __shared__ float s_scr[16 * 4 * 64];  // 16KB: [w][k][lane]
    s_qpT[t] = qpt[(size_t)b * 1024 + t];
    __syncthreads();
    float4 qp[4][4];  // [j: col-quad][k: head] -> 64 floats
    #pragma unroll
    for (int k = 0; k < 4; ++k)
        #pragma unroll
        for (int j = 0; j < 4; ++j)
            qp[j][k] = *(const float4*)&s_qpT[(hb + k) * 128 + cs * 16 + 4 * j];
    const int use32 = *mflag;
    const unsigned char* mk8 = (const unsigned char*)maskp + (size_t)b * NN;
    const int* mk32 = (const int*)maskp + (size_t)b * NN;
    for (int nb = 0; nb < 2; ++nb) {
        const int row = nb * 64 + lane;
        float acc[4] = {0.f, 0.f, 0.f, 0.f};
        if (row < 125) {
            #pragma unroll
            for (int j = 0; j < 4; ++j) {
                const float4 e = *(const float4*)(eb + (size_t)(s * 125 + row) * DD + cs * 16 + 4 * j);
                #pragma unroll
                for (int k = 0; k < 4; ++k) {
                    acc[k] = fmaf(e.x, qp[j][k].x, acc[k]);
                    acc[k] = fmaf(e.y, qp[j][k].y, acc[k]);
                    acc[k] = fmaf(e.z, qp[j][k].z, acc[k]);
                    acc[k] = fmaf(e.w, qp[j][k].w, acc[k]);
                }
            }
        }
        #pragma unroll
        for (int k = 0; k < 4; ++k) s_scr[(w * 4 + k) * 64 + lane] = acc[k];
        __syncthreads();
        if (t < 512) {
            const int h = t >> 6, l = t & 63;
            const int r2 = nb * 64 + l;
            if (r2 < 125) {
                float c = 0.f;
                #pragma unroll
                for (int c8 = 0; c8 < 8; ++c8)
                    c += s_scr[((c8 * 2 + (h >> 2)) * 4 + (h & 3)) * 64 + l];
                const int n = s * 125 + r2;
                const bool m = use32 ? (mk32[n] != 0) : (mk8[n] != 0);
                compat[(size_t)b * 8192 + h * 1024 + n] = m ? NEG_BIG : c;
            }
        }
        __syncthreads();
    }
}

// ---------------- K3: softmax stats + wemb partials [b][s][h][i] ----------------
__global__ __launch_bounds__(512, 4)
void k3_wembp(const float* __restrict__ emb, const float* __restrict__ compat,
              float* __restrict__ wembp) {
    const int b = blockIdx.x >> 3, s = blockIdx.x & 7;
    const int t = threadIdx.x, w = t >> 6, lane = t & 63;
    const float* eb = emb + (size_t)b * (NN * DD);
    __shared__ float s_m[8], s_sinv[8];
    __shared__ __align__(16) float s_attn[125 * 8];   // [nl][h]
    __shared__ float s_part[8 * 8 * 132];             // [w][h][132]
    {   // wave w: global max/sum for head w over all 1000 (redundant across s, cheap)
        const float* ch = compat + (size_t)b * 8192 + (size_t)w * 1024;
        float m = NEG_BIG;
        for (int n = lane; n < NN; n += 64) m = fmaxf(m, ch[n]);
        #pragma unroll
        for (int o = 32; o; o >>= 1) m = fmaxf(m, __shfl_xor(m, o, 64));
        float sum = 0.f;
        for (int n = lane; n < NN; n += 64) sum += expf(ch[n] - m);
        #pragma unroll
        for (int o = 32; o; o >>= 1) sum += __shfl_xor(sum, o, 64);
        if (lane == 0) { s_m[w] = m; s_sinv[w] = 1.0f / sum; }
    }
    __syncthreads();
    for (int idx = t; idx < 125 * 8; idx += 512) {
        const int nl = idx >> 3, h = idx & 7;
        const int n = s * 125 + nl;
        s_attn[idx] = expf(compat[(size_t)b * 8192 + h * 1024 + n] - s_m[h]) * s_sinv[h];
    }
    __syncthreads();
    {   // outer product: lane owns cols {2l, 2l+1}, wave strides rows
        float a0[8] = {0,0,0,0,0,0,0,0}, a1[8] = {0,0,0,0,0,0,0,0};
        for (int nl = w; nl < 125; nl += 8) {
            const float2 e  = *(const float2*)(eb + (size_t)(s * 125 + nl) * DD + 2 * lane);
            const float4 p0 = *(const float4*)&s_attn[nl * 8];
            const float4 p1 = *(const float4*)&s_attn[nl * 8 + 4];
            a0[0] = fmaf(e.x, p0.x, a0[0]); a1[0] = fmaf(e.y, p0.x, a1[0]);
            a0[1] = fmaf(e.x, p0.y, a0[1]); a1[1] = fmaf(e.y, p0.y, a1[1]);
            a0[2] = fmaf(e.x, p0.z, a0[2]); a1[2] = fmaf(e.y, p0.z, a1[2]);
            a0[3] = fmaf(e.x, p0.w, a0[3]); a1[3] = fmaf(e.y, p0.w, a1[3]);
            a0[4] = fmaf(e.x, p1.x, a0[4]); a1[4] = fmaf(e.y, p1.x, a1[4]);
            a0[5] = fmaf(e.x, p1.y, a0[5]); a1[5] = fmaf(e.y, p1.y, a1[5]);
            a0[6] = fmaf(e.x, p1.z, a0[6]); a1[6] = fmaf(e.y, p1.z, a1[6]);
            a0[7] = fmaf(e.x, p1.w, a0[7]); a1[7] = fmaf(e.y, p1.w, a1[7]);
        }
        #pragma unroll
        for (int h = 0; h < 8; ++h) {
            s_part[(w * 8 + h) * 132 + 2 * lane]     = a0[h];
            s_part[(w * 8 + h) * 132 + 2 * lane + 1] = a1[h];
        }
    }
    __syncthreads();
    for (int idx = t; idx < 1024; idx += 512) {
        const int h = idx >> 7, i = idx & 127;
        float v = 0.f;
        #pragma unroll
        for (int g = 0; g < 8; ++g) v += s_part[(g * 8 + h) * 132 + i];
        wembp[(size_t)b * 8192 + s * 1024 + idx] = v;   // [b][s][h][i]
    }
}

// ---------------- K4: wemb finalize -> heads -> glimpse -> g2 -> logits ----------------
__global__ __launch_bounds__(512, 4)
void k4_logits(const float* __restrict__ emb, const float* __restrict__ wembp,
               const float* __restrict__ Wn, const float* __restrict__ Wo,
               const void* __restrict__ maskp, const int* __restrict__ mflag,
               float* __restrict__ logits) {
    const int b = blockIdx.x >> 3, s = blockIdx.x & 7;
    const int t = threadIdx.x, w = t >> 6, lane = t & 63;
    const float* eb = emb + (size_t)b * (NN * DD);
    __shared__ float s_wemb[8 * 130];   // [h][130]
    __shared__ float s_red[512];
    __shared__ float s_heads[128], s_gl[128], s_g2[128];
    __shared__ float s_scr[512];
    for (int idx = t; idx < 1024; idx += 512) {
        float v = 0.f;
        #pragma unroll
        for (int g = 0; g < 8; ++g) v += wembp[(size_t)b * 8192 + g * 1024 + idx];
        s_wemb[(idx >> 7) * 130 + (idx & 127)] = v;
    }
    __syncthreads();
    {   // heads[j] = sum_i Wv[i,j] wemb[j>>4][i]
        const int j = t & 127, p = t >> 7;
        float a = 0.f;
        for (int i = 32 * p; i < 32 * p + 32; ++i)
            a = fmaf(Wn[i * 384 + 128 + j], s_wemb[(j >> 4) * 130 + i], a);
        s_red[p * 128 + j] = a;
    }
    __syncthreads();
    if (t < 128) s_heads[t] = s_red[t] + s_red[128 + t] + s_red[256 + t] + s_red[384 + t];
    __syncthreads();
    {   // glimpse[d] = sum_j heads[j] Wo[j,d]
        const int d = t & 127, p = t >> 7;
        float a = 0.f;
        for (int j = 32 * p; j < 32 * p + 32; ++j)
            a = fmaf(s_heads[j], Wo[j * DD + d], a);
        s_red[p * 128 + d] = a;
    }
    __syncthreads();
    if (t < 128) s_gl[t] = s_red[t] + s_red[128 + t] + s_red[256 + t] + s_red[384 + t];
    __syncthreads();
    {   // g2[i] = (1/sqrt(128)) sum_d Wl[i,d] glimpse[d]
        const int i = t & 127, p = t >> 7;
        float a = 0.f;
        for (int d = 32 * p; d < 32 * p + 32; ++d)
            a = fmaf(Wn[i * 384 + 256 + d], s_gl[d], a);
        s_red[p * 128 + i] = a;
    }
    __syncthreads();
    if (t < 128)
        s_g2[t] = (s_red[t] + s_red[128 + t] + s_red[256 + t] + s_red[384 + t]) * 0.08838834764831845f;
    __syncthreads();
    const int use32 = *mflag;
    const unsigned char* mk8 = (const unsigned char*)maskp + (size_t)b * NN;
    const int* mk32 = (const int*)maskp + (size_t)b * NN;
    float g2r[16];
    #pragma unroll
    for (int ii = 0; ii < 16; ++ii) g2r[ii] = s_g2[w * 16 + ii];
    for (int nb = 0; nb < 2; ++nb) {
        const int row = nb * 64 + lane;
        float acc = 0.f;
        if (row < 125) {
            #pragma unroll
            for (int j = 0; j < 4; ++j) {
                const float4 e = *(const float4*)(eb + (size_t)(s * 125 + row) * DD + w * 16 + 4 * j);
                acc = fmaf(e.x, g2r[4 * j + 0], acc);
                acc = fmaf(e.y, g2r[4 * j + 1], acc);
                acc = fmaf(e.z, g2r[4 * j + 2], acc);
                acc = fmaf(e.w, g2r[4 * j + 3], acc);
            }
        }
        s_scr[w * 64 + lane] = acc;
        __syncthreads();
        if (t < 64) {
            const int r2 = nb * 64 + t;
            if (r2 < 125) {
                float x = 0.f;
                #pragma unroll
                for (int g = 0; g < 8; ++g) x += s_scr[g * 64 + t];
                const int n = s * 125 + r2;
                const bool m = use32 ? (mk32[n] != 0) : (mk8[n] != 0);
                logits[(size_t)b * 1024 + n] = m ? NEG_BIG : 10.0f * tanhf(x);
            }
        }
        __syncthreads();
    }
}

// ---------------- K5: per-batch log_softmax ----------------
__global__ __launch_bounds__(512, 4)
void k5_logsoftmax(const float* __restrict__ logits, float* __restrict__ out) {
    const int b = blockIdx.x, t = threadIdx.x, w = t >> 6, lane = t & 63;
    __shared__ float s_red[16];
    __shared__ float s_lse;
    const float* lg = logits + (size_t)b * 1024;
    float m = NEG_BIG;
    for (int n = t; n < NN; n += 512) m = fmaxf(m, lg[n]);
    #pragma unroll
    for (int o = 32; o; o >>= 1) m = fmaxf(m, __shfl_xor(m, o, 64));
    if (lane == 0) s_red[w] = m;
    __syncthreads();
    if (t == 0) {
        float mm = s_red[0];
        #pragma unroll
        for (int i = 1; i < 8; ++i) mm = fmaxf(mm, s_red[i]);
        s_red[8] = mm;
    }
    __syncthreads();
    const float mb = s_red[8];
    float sum = 0.f;
    for (int n = t; n < NN; n += 512) sum += expf(lg[n] - mb);
    #pragma unroll
    for (int o = 32; o; o >>= 1) sum += __shfl_xor(sum, o, 64);
    __syncthreads();
    if (lane == 0) s_red[w] = sum;
    __syncthreads();
    if (t == 0) {
        float ss = 0.f;
        #pragma unroll
        for (int i = 0; i < 8; ++i) ss += s_red[i];
        s_lse = mb + logf(ss);
    }
    __syncthreads();
    const float lse = s_lse;
    float* ob = out + (size_t)b * NN;
    for (int n = t; n < NN; n += 512) ob[n] = lg[n] - lse;
}

// ============================================================================
// Fallback: round-2 fused kernel (proven correct), used only if ws too small.
// ============================================================================
__global__ __launch_bounds__(512, 2)
void attn_model_fused(const float* __restrict__ emb, const float* __restrict__ stepc,
                      const void* __restrict__ maskp,
                      const float* __restrict__ Wn, const float* __restrict__ Wf,
                      const float* __restrict__ Ws, const float* __restrict__ Wo,
                      float* __restrict__ out) {
    const int b = blockIdx.x, t = threadIdx.x, w = t >> 6, lane = t & 63;
    const float* eb = emb + (size_t)b * (NN * DD);
    __shared__ __align__(16) float s_compat[8 * 1024];
    __shared__ __align__(16) float s_attn[NN * 8];
    __shared__ __align__(16) float s_scr[4096];
    __shared__ float s_mean[DD], s_q[DD];
    __shared__ __align__(16) float s_qproj[DD * 8];
    __shared__ float s_wemb[DD * 8], s_heads[DD], s_glimpse[DD], s_g2[DD];
    __shared__ float s_logits[NN], s_m[8], s_s[8], s_red[16], s_lse;
    __shared__ int s_mask_is_int;
    if (t == 0) {
        const unsigned char* mb8 = (const unsigned char*)maskp;
        int any = 0;
        for (int k = 0; k < 64; ++k) any |= mb8[4 * k + 1];
        s_mask_is_int = (any == 0) ? 1 : 0;
    }
    __syncthreads();
    const int mask_is_int = s_mask_is_int;
    const unsigned char* mk8 = (const unsigned char*)maskp + (size_t)b * NN;
    const int* mk32 = (const int*)maskp + (size_t)b * NN;
#define MASKED(n) (mask_is_int ? (mk32[(n)] != 0) : (mk8[(n)] != 0))
    {
        const int c4 = t & 31, r0 = t >> 5;
        float4 a = make_float4(0.f, 0.f, 0.f, 0.f);
        for (int n = r0; n < NN; n += 16) {
            const float4 v = *(const float4*)(eb + n * DD + c4 * 4);
            a.x += v.x; a.y += v.y; a.z += v.z; a.w += v.w;
        }
        ((float4*)s_scr)[r0 * 32 + c4] = a;
    }
    __syncthreads();
    if (t < DD) {
        float s = 0.f;
        #pragma unroll
        for (int g = 0; g < 16; ++g) s += s_scr[g * 128 + t];
        s_mean[t] = s * (1.0f / (float)NN);
    }
    __syncthreads();
    {
        const int d = t & 127, p = t >> 7;
        float a = 0.f;
        for (int i = 32 * p; i < 32 * p + 32; ++i) a = fmaf(s_mean[i], Wf[i * DD + d], a);
        const float* scb = stepc + (size_t)b * CTXN;
        const int c0 = 32 * p, c1 = (p == 3) ? CTXN : 32 * p + 32;
        for (int c = c0; c < c1; ++c) a = fmaf(scb[c], Ws[c * DD + d], a);
        s_scr[p * 128 + d] = a;
    }
    __syncthreads();
    if (t < DD) s_q[t] = s_scr[t] + s_scr[128 + t] + s_scr[256 + t] + s_scr[384 + t];
    __syncthreads();
    {
        const int i = t & 127, hh = t >> 7;
        #pragma unroll
        for (int u = 0; u < 2; ++u) {
            const int h = hh + 4 * u;
            float a = 0.f;
            #pragma unroll
            for (int j = 0; j < 16; ++j) a = fmaf(Wn[i * 384 + h * 16 + j], s_q[h * 16 + j], a);
            s_qproj[i * 8 + h] = a * 0.25f;
        }
    }
    __syncthreads();
    {
        float qp[16][8];
        #pragma unroll
        for (int ii = 0; ii < 16; ++ii)
            #pragma unroll
            for (int h = 0; h < 8; ++h) qp[ii][h] = s_qproj[(w * 16 + ii) * 8 + h];
        for (int nb = 0; nb < 16; ++nb) {
            const int row = nb * 64 + lane;
            float acc[8] = {0,0,0,0,0,0,0,0};
            if (row < NN) {
                #pragma unroll
                for (int j = 0; j < 4; ++j) {
                    const float4 e = *(const float4*)(eb + row * DD + w * 16 + j * 4);
                    #pragma unroll
                    for (int h = 0; h < 8; ++h) {
                        acc[h] = fmaf(e.x, qp[4 * j + 0][h], acc[h]);
                        acc[h] = fmaf(e.y, qp[4 * j + 1][h], acc[h]);
                        acc[h] = fmaf(e.z, qp[4 * j + 2][h], acc[h]);
                        acc[h] = fmaf(e.w, qp[4 * j + 3][h], acc[h]);
                    }
                }
            }
            #pragma unroll
            for (int h = 0; h < 8; ++h) s_scr[(w * 8 + h) * 64 + lane] = acc[h];
            __syncthreads();
            {
                const int h = t >> 6, l = t & 63;
                const int rr = nb * 64 + l;
                if (rr < NN) {
                    float c = 0.f;
                    #pragma unroll
                    for (int w2 = 0; w2 < 8; ++w2) c += s_scr[(w2 * 8 + h) * 64 + l];
                    s_compat[h * 1024 + rr] = MASKED(rr) ? NEG_BIG : c;
                }
            }
            __syncthreads();
        }
    }
    {
        const int h = w;
        float m = NEG_BIG;
        for (int n = lane; n < NN; n += 64) m = fmaxf(m, s_compat[h * 1024 + n]);
        #pragma unroll
        for (int s = 32; s; s >>= 1) m = fmaxf(m, __shfl_xor(m, s, 64));
        float sum = 0.f;
        for (int n = lane; n < NN; n += 64) sum += expf(s_compat[h * 1024 + n] - m);
        #pragma unroll
        for (int s = 32; s; s >>= 1) sum += __shfl_xor(sum, s, 64);
        if (lane == 0) { s_m[h] = m; s_s[h] = 1.0f / sum; }
    }
    __syncthreads();
    for (int n = t; n < NN; n += 512) {
        #pragma unroll
        for (int h = 0; h < 8; ++h) s_attn[n * 8 + h] = expf(s_compat[h * 1024 + n] - s_m[h]) * s_s[h];
    }
    __syncthreads();
    {
        float a0[8] = {0,0,0,0,0,0,0,0}, a1[8] = {0,0,0,0,0,0,0,0};
        for (int n = w; n < NN; n += 8) {
            const float2 e = *(const float2*)(eb + n * DD + 2 * lane);
            const float4 p0 = *(const float4*)(&s_attn[n * 8]);
            const float4 p1 = *(const float4*)(&s_attn[n * 8 + 4]);
            a0[0] = fmaf(e.x, p0.x, a0[0]); a1[0] = fmaf(e.y, p0.x, a1[0]);
            a0[1] = fmaf(e.x, p0.y, a0[1]); a1[1] = fmaf(e.y, p0.y, a1[1]);
            a0[2] = fmaf(e.x, p0.z, a0[2]); a1[2] = fmaf(e.y, p0.z, a1[2]);
            a0[3] = fmaf(e.x, p0.w, a0[3]); a1[3] = fmaf(e.y, p0.w, a1[3]);
            a0[4] = fmaf(e.x, p1.x, a0[4]); a1[4] = fmaf(e.y, p1.x, a1[4]);
            a0[5] = fmaf(e.x, p1.y, a0[5]); a1[5] = fmaf(e.y, p1.y, a1[5]);
            a0[6] = fmaf(e.x, p1.z, a0[6]); a1[6] = fmaf(e.y, p1.z, a1[6]);
            a0[7] = fmaf(e.x, p1.w, a0[7]); a1[7] = fmaf(e.y, p1.w, a1[7]);
        }
        #pragma unroll
        for (int h = 0; h < 8; ++h)
            *(float2*)&s_compat[(w * 8 + h) * 128 + 2 * lane] = make_float2(a0[h], a1[h]);
    }
    __syncthreads();
    {
        const int i = t & 127, h2 = t >> 7;
        #pragma unroll
        for (int u = 0; u < 2; ++u) {
            const int h = h2 + 4 * u;
            float a = 0.f;
            #pragma unroll
            for (int w2 = 0; w2 < 8; ++w2) a += s_compat[(w2 * 8 + h) * 128 + i];
            s_wemb[i * 8 + h] = a;
        }
    }
    __syncthreads();
    if (t < DD) {
        const int h = t >> 4;
        float a = 0.f;
        for (int i = 0; i < DD; ++i) a = fmaf(Wn[i * 384 + 128 + t], s_wemb[i * 8 + h], a);
        s_heads[t] = a;
    }
    __syncthreads();
    if (t < DD) {
        float a = 0.f;
        for (int j = 0; j < DD; ++j) a = fmaf(s_heads[j], Wo[j * DD + t], a);
        s_glimpse[t] = a;
    }
    __syncthreads();
    if (t < DD) {
        float a = 0.f;
        for (int d = 0; d < DD; ++d) a = fmaf(Wn[t * 384 + 256 + d], s_glimpse[d], a);
        s_g2[t] = a * 0.08838834764831845f;
    }
    __syncthreads();
    {
        float g2r[16];
        #pragma unroll
        for (int ii = 0; ii < 16; ++ii) g2r[ii] = s_g2[w * 16 + ii];
        for (int nb = 0; nb < 16; ++nb) {
            const int row = nb * 64 + lane;
            float acc = 0.f;
            if (row < NN) {
                #pragma unroll
                for (int j = 0; j < 4; ++j) {
                    const float4 e = *(const float4*)(eb + row * DD + w * 16 + j * 4);
                    acc = fmaf(e.x, g2r[4 * j + 0], acc);
                    acc = fmaf(e.y, g2r[4 * j + 1], acc);
                    acc = fmaf(e.z, g2r[4 * j + 2], acc);
                    acc = fmaf(e.w, g2r[4 * j + 3], acc);
                }
            }
            s_scr[w * 64 + lane] = acc;
            __syncthreads();
            if (t < 64) {
                const int rr = nb * 64 + t;
                if (rr < NN) {
                    float x = 0.f;
                    #pragma unroll
                    for (int w2 = 0; w2 < 8; ++w2) x += s_scr[w2 * 64 + t];
                    s_logits[rr] = MASKED(rr) ? NEG_BIG : 10.0f * tanhf(x);
                }
            }
            __syncthreads();
        }
    }
    {
        float m = NEG_BIG;
        for (int n = t; n < NN; n += 512) m = fmaxf(m, s_logits[n]);
        #pragma unroll
        for (int s = 32; s; s >>= 1) m = fmaxf(m, __shfl_xor(m, s, 64));
        if (lane == 0) s_red[w] = m;
        __syncthreads();
        if (t == 0) {
            float mm = s_red[0];
            #pragma unroll
            for (int i = 1; i < 8; ++i) mm = fmaxf(mm, s_red[i]);
            s_red[8] = mm;
        }
        __syncthreads();
        const float mb = s_red[8];
        float sum = 0.f;
        for (int n = t; n < NN; n += 512) sum += expf(s_logits[n] - mb);
        #pragma unroll
        for (int s = 32; s; s >>= 1) sum += __shfl_xor(sum, s, 64);
        __syncthreads();
        if (lane == 0) s_red[w] = sum;
        __syncthreads();
        if (t == 0) {
            float ss = 0.f;
            #pragma unroll
            for (int i = 0; i < 8; ++i) ss += s_red[i];
            s_lse = mb + logf(ss);
        }
        __syncthreads();
        const float lse = s_lse;
        float* ob = out + (size_t)b * NN;
        for (int n = t; n < NN; n += 512) ob[n] = s_logits[n] - lse;
    }
#undef MASKED
}

extern "C" void kernel_launch(void* const* d_in, const int* in_sizes, int n_in,
                              void* d_out, int out_size, void* d_ws, size_t ws_size,
                              hipStream_t stream) {
    const float* emb   = (const float*)d_in[0];
    const float* stepc = (const float*)d_in[1];
    const void*  mask  = (const void*)d_in[2];
    const float* Wn = (const float*)d_in[3];
    const float* Wf = (const float*)d_in[4];
    const float* Ws = (const float*)d_in[5];
    const float* Wo = (const float*)d_in[6];
    float* out = (float*)d_out;
    const int B = in_sizes[0] / (NN * DD);  // 256

    // ws layout (floats)
    float* wsf = (float*)d_ws;
    const size_t n_meanp = (size_t)B * 1024;
    const size_t n_qpt   = (size_t)B * 1024;
    const size_t n_comp  = (size_t)B * 8192;
    const size_t n_wembp = (size_t)B * 8192;
    const size_t n_logit = (size_t)B * 1024;
    const size_t need = (n_meanp + n_qpt + n_comp + n_wembp + n_logit + 16) * sizeof(float);

    if (ws_size < need) {
        attn_model_fused<<<B, 512, 0, stream>>>(emb, stepc, mask, Wn, Wf, Ws, Wo, out);
        return;
    }
    float* meanp  = wsf;
    float* qpt    = meanp + n_meanp;
    float* compat = qpt + n_qpt;
    float* wembp  = compat + n_comp;
    float* logits = wembp + n_wembp;
    int*   mflag  = (int*)(logits + n_logit);

    k1_meanpart  <<<B * 8, 256, 0, stream>>>(emb, meanp);
    k1b_qproj    <<<B,     512, 0, stream>>>(meanp, stepc, mask, Wn, Wf, Ws, qpt, mflag);
    k2_compat    <<<B * 8, 1024, 0, stream>>>(emb, qpt, mask, mflag, compat);
    k3_wembp     <<<B * 8, 512, 0, stream>>>(emb, compat, wembp);
    k4_logits    <<<B * 8, 512, 0, stream>>>(emb, wembp, Wn, Wo, mask, mflag, logits);
    k5_logsoftmax<<<B,     512, 0, stream>>>(logits, out);
}

// Round 4
// 140.597 us; speedup vs baseline: 1.5758x; 1.5758x over previous
//
#include <hip/hip_runtime.h>
#include <math.h>

#define NN   1000
#define DD   128
#define CTXN 130
#define NEG_BIG (-1.0e30f)

// ============================================================================
// Pipeline (all emb reads coalesced: 4 consecutive rows per wave instruction):
//  k1  (B*8 blk): per-slice column sums of emb           (emb pass 1)
//  k1b (B blk)  : mean -> query -> qproj[h][i], mask probe
//  k2  (B*8 blk): compat[b][n][h] = emb_n . qproj[:,h]   (emb pass 2)
//  k2b (B blk)  : per-head softmax max / 1/sum
//  k3  (B*8 blk): attn + wemb partials [b][s][h][i]      (emb pass 3)
//  k4a (B blk)  : wemb -> heads -> glimpse -> g2
//  k4b (B*8 blk): logits[n] = 10*tanh(emb_n . g2)        (emb pass 4)
//  k5  (B blk)  : log_softmax
// ws: meanp[B][1024] | qpt[B][1024] | compat[B][8192] | wembp[B][8192]
//     | g2v[B][128] | stats[B][16] | logits[B][1024] | mflag
// ============================================================================

// ---------------- K1: per-(b,s) partial column sums ----------------
__global__ __launch_bounds__(256, 8)
void k1_meanpart(const float* __restrict__ emb, float* __restrict__ meanp) {
    const int b = blockIdx.x >> 3, s = blockIdx.x & 7;
    const int t = threadIdx.x;
    const float* eb = emb + (size_t)b * (NN * DD);
    __shared__ __align__(16) float s_red[8 * 128];
    const int c4 = t & 31, rg = t >> 5;
    float4 a = make_float4(0.f, 0.f, 0.f, 0.f);
    for (int nl = rg; nl < 125; nl += 8) {
        const float4 v = *(const float4*)(eb + (size_t)(s * 125 + nl) * DD + c4 * 4);
        a.x += v.x; a.y += v.y; a.z += v.z; a.w += v.w;
    }
    ((float4*)s_red)[rg * 32 + c4] = a;
    __syncthreads();
    if (t < 128) {
        float v = 0.f;
        #pragma unroll
        for (int g = 0; g < 8; ++g) v += s_red[g * 128 + t];
        meanp[(size_t)b * 1024 + s * 128 + t] = v;
    }
}

// ---------------- K1b: mean -> query -> qproj [h][i], + mask layout probe ----------------
__global__ __launch_bounds__(512, 4)
void k1b_qproj(const float* __restrict__ meanp, const float* __restrict__ stepc,
               const void* __restrict__ maskp,
               const float* __restrict__ Wn, const float* __restrict__ Wf,
               const float* __restrict__ Ws,
               float* __restrict__ qpt, int* __restrict__ mflag) {
    const int b = blockIdx.x, t = threadIdx.x;
    __shared__ float s_mean[128], s_q[128];
    __shared__ float s_red[512];
    if (b == 0 && t == 0) {   // int32 mask: bytes at 1 mod 4 are always 0
        const unsigned char* mb8 = (const unsigned char*)maskp;
        int any = 0;
        for (int k = 0; k < 64; ++k) any |= mb8[4 * k + 1];
        *mflag = (any == 0) ? 1 : 0;
    }
    if (t < 128) {
        float v = 0.f;
        #pragma unroll
        for (int g = 0; g < 8; ++g) v += meanp[(size_t)b * 1024 + g * 128 + t];
        s_mean[t] = v * (1.0f / (float)NN);
    }
    __syncthreads();
    {   // query[d] = sum_i mean[i] Wf[i,d] + sum_c sc[c] Ws[c,d]
        const int d = t & 127, p = t >> 7;
        float a = 0.f;
        for (int i = 32 * p; i < 32 * p + 32; ++i)
            a = fmaf(s_mean[i], Wf[i * DD + d], a);
        const float* scb = stepc + (size_t)b * CTXN;
        const int c0 = 32 * p, c1 = (p == 3) ? CTXN : 32 * p + 32;
        for (int c = c0; c < c1; ++c)
            a = fmaf(scb[c], Ws[c * DD + d], a);
        s_red[p * 128 + d] = a;
    }
    __syncthreads();
    if (t < 128) s_q[t] = s_red[t] + s_red[128 + t] + s_red[256 + t] + s_red[384 + t];
    __syncthreads();
    {   // qpt[b][h][i] = 0.25 * sum_j Wn[i, 16h+j] q[16h+j]
        const int i = t & 127, p = t >> 7;
        #pragma unroll
        for (int u = 0; u < 2; ++u) {
            const int h = p + 4 * u;
            float a = 0.f;
            #pragma unroll
            for (int j = 0; j < 16; ++j)
                a = fmaf(Wn[i * 384 + h * 16 + j], s_q[h * 16 + j], a);
            qpt[(size_t)b * 1024 + h * 128 + i] = a * 0.25f;
        }
    }
}

// ---------------- K2: compat[b][n][h], coalesced 4-rows-x-16-lanes ----------------
__global__ __launch_bounds__(512, 2)
void k2_compat(const float* __restrict__ emb, const float* __restrict__ qpt,
               const void* __restrict__ maskp, const int* __restrict__ mflag,
               float* __restrict__ compat) {
    const int b = blockIdx.x >> 3, s = blockIdx.x & 7;
    const int t = threadIdx.x, w = t >> 6, lane = t & 63;
    const int rg = lane >> 4, cl = lane & 15;
    const float* eb = emb + (size_t)b * (NN * DD);
    __shared__ __align__(16) float s_qpT[1024];
    for (int i = t; i < 1024; i += 512) s_qpT[i] = qpt[(size_t)b * 1024 + i];
    __syncthreads();
    float4 qa[8], qb[8];   // qproj cols cl*8..cl*8+7 for all 8 heads (64 VGPR)
    #pragma unroll
    for (int h = 0; h < 8; ++h) {
        qa[h] = *(const float4*)&s_qpT[h * 128 + cl * 8];
        qb[h] = *(const float4*)&s_qpT[h * 128 + cl * 8 + 4];
    }
    const int use32 = *mflag;
    const unsigned char* mk8 = (const unsigned char*)maskp + (size_t)b * NN;
    const int* mk32 = (const int*)maskp + (size_t)b * NN;
    #pragma unroll
    for (int it = 0; it < 4; ++it) {
        const int r = w * 16 + it * 4 + rg;     // 0..127 (valid < 125)
        const int n = s * 125 + r;
        float acc[8] = {0.f,0.f,0.f,0.f,0.f,0.f,0.f,0.f};
        if (r < 125) {
            const float4 e0 = *(const float4*)(eb + (size_t)n * DD + cl * 8);
            const float4 e1 = *(const float4*)(eb + (size_t)n * DD + cl * 8 + 4);
            #pragma unroll
            for (int h = 0; h < 8; ++h) {
                float a = e0.x * qa[h].x;
                a = fmaf(e0.y, qa[h].y, a);
                a = fmaf(e0.z, qa[h].z, a);
                a = fmaf(e0.w, qa[h].w, a);
                a = fmaf(e1.x, qb[h].x, a);
                a = fmaf(e1.y, qb[h].y, a);
                a = fmaf(e1.z, qb[h].z, a);
                a = fmaf(e1.w, qb[h].w, a);
                acc[h] = a;
            }
        }
        #pragma unroll
        for (int h = 0; h < 8; ++h) {   // reduce over the 16 col-lanes
            acc[h] += __shfl_xor(acc[h], 1, 16);
            acc[h] += __shfl_xor(acc[h], 2, 16);
            acc[h] += __shfl_xor(acc[h], 4, 16);
            acc[h] += __shfl_xor(acc[h], 8, 16);
        }
        if (cl == 0 && r < 125) {
            const bool m = use32 ? (mk32[n] != 0) : (mk8[n] != 0);
            float4 o0, o1;
            if (m) { o0 = make_float4(NEG_BIG, NEG_BIG, NEG_BIG, NEG_BIG); o1 = o0; }
            else   { o0 = make_float4(acc[0], acc[1], acc[2], acc[3]);
                     o1 = make_float4(acc[4], acc[5], acc[6], acc[7]); }
            *(float4*)&compat[(size_t)b * 8192 + (size_t)n * 8]     = o0;
            *(float4*)&compat[(size_t)b * 8192 + (size_t)n * 8 + 4] = o1;
        }
    }
}

// ---------------- K2b: per-(b,head) softmax stats, once per b ----------------
__global__ __launch_bounds__(512, 4)
void k2b_stats(const float* __restrict__ compat, float* __restrict__ stats) {
    const int b = blockIdx.x, t = threadIdx.x, w = t >> 6, lane = t & 63;
    const float* cb = compat + (size_t)b * 8192;
    float m = NEG_BIG;
    for (int n = lane; n < NN; n += 64) m = fmaxf(m, cb[n * 8 + w]);
    #pragma unroll
    for (int o = 32; o; o >>= 1) m = fmaxf(m, __shfl_xor(m, o, 64));
    float sum = 0.f;
    for (int n = lane; n < NN; n += 64) sum += expf(cb[n * 8 + w] - m);
    #pragma unroll
    for (int o = 32; o; o >>= 1) sum += __shfl_xor(sum, o, 64);
    if (lane == 0) { stats[b * 16 + w] = m; stats[b * 16 + 8 + w] = 1.0f / sum; }
}

// ---------------- K3: attn + wemb partials [b][s][h][i] ----------------
__global__ __launch_bounds__(512, 4)
void k3_wembp(const float* __restrict__ emb, const float* __restrict__ compat,
              const float* __restrict__ stats, float* __restrict__ wembp) {
    const int b = blockIdx.x >> 3, s = blockIdx.x & 7;
    const int t = threadIdx.x, w = t >> 6, lane = t & 63;
    const float* eb = emb + (size_t)b * (NN * DD);
    __shared__ float s_m[8], s_sinv[8];
    __shared__ __align__(16) float s_attn[125 * 8];   // [nl][h]
    __shared__ float s_part[8 * 8 * 132];             // [w][h][132]
    if (t < 8)       s_m[t]        = stats[b * 16 + t];
    else if (t < 16) s_sinv[t - 8] = stats[b * 16 + t];
    __syncthreads();
    for (int idx = t; idx < 1000; idx += 512) {       // compat [n][h] contiguous
        const int h = idx & 7;
        s_attn[idx] = expf(compat[(size_t)b * 8192 + (size_t)s * 1000 + idx] - s_m[h]) * s_sinv[h];
    }
    __syncthreads();
    {   // outer product: lane owns cols {2l,2l+1}, wave strides rows (coalesced)
        float a0[8] = {0,0,0,0,0,0,0,0}, a1[8] = {0,0,0,0,0,0,0,0};
        for (int nl = w; nl < 125; nl += 8) {
            const float2 e  = *(const float2*)(eb + (size_t)(s * 125 + nl) * DD + 2 * lane);
            const float4 p0 = *(const float4*)&s_attn[nl * 8];
            const float4 p1 = *(const float4*)&s_attn[nl * 8 + 4];
            a0[0] = fmaf(e.x, p0.x, a0[0]); a1[0] = fmaf(e.y, p0.x, a1[0]);
            a0[1] = fmaf(e.x, p0.y, a0[1]); a1[1] = fmaf(e.y, p0.y, a1[1]);
            a0[2] = fmaf(e.x, p0.z, a0[2]); a1[2] = fmaf(e.y, p0.z, a1[2]);
            a0[3] = fmaf(e.x, p0.w, a0[3]); a1[3] = fmaf(e.y, p0.w, a1[3]);
            a0[4] = fmaf(e.x, p1.x, a0[4]); a1[4] = fmaf(e.y, p1.x, a1[4]);
            a0[5] = fmaf(e.x, p1.y, a0[5]); a1[5] = fmaf(e.y, p1.y, a1[5]);
            a0[6] = fmaf(e.x, p1.z, a0[6]); a1[6] = fmaf(e.y, p1.z, a1[6]);
            a0[7] = fmaf(e.x, p1.w, a0[7]); a1[7] = fmaf(e.y, p1.w, a1[7]);
        }
        #pragma unroll
        for (int h = 0; h < 8; ++h)
            *(float2*)&s_part[(w * 8 + h) * 132 + 2 * lane] = make_float2(a0[h], a1[h]);
    }
    __syncthreads();
    for (int idx = t; idx < 1024; idx += 512) {
        const int h = idx >> 7, i = idx & 127;
        float v = 0.f;
        #pragma unroll
        for (int g = 0; g < 8; ++g) v += s_part[(g * 8 + h) * 132 + i];
        wembp[(size_t)b * 8192 + s * 1024 + idx] = v;   // [b][s][h][i]
    }
}

// ---------------- K4a: wemb -> heads -> glimpse -> g2 (once per b) ----------------
__global__ __launch_bounds__(512, 4)
void k4a_g2(const float* __restrict__ wembp, const float* __restrict__ Wn,
            const float* __restrict__ Wo, float* __restrict__ g2v) {
    const int b = blockIdx.x, t = threadIdx.x;
    __shared__ float s_wemb[8 * 130];   // [h][130]
    __shared__ float s_red[512];
    __shared__ float s_heads[128], s_gl[128];
    for (int idx = t; idx < 1024; idx += 512) {
        float v = 0.f;
        #pragma unroll
        for (int g = 0; g < 8; ++g) v += wembp[(size_t)b * 8192 + g * 1024 + idx];
        s_wemb[(idx >> 7) * 130 + (idx & 127)] = v;
    }
    __syncthreads();
    {   // heads[j] = sum_i Wv[i,j] wemb[j>>4][i]
        const int j = t & 127, p = t >> 7;
        float a = 0.f;
        for (int i = 32 * p; i < 32 * p + 32; ++i)
            a = fmaf(Wn[i * 384 + 128 + j], s_wemb[(j >> 4) * 130 + i], a);
        s_red[p * 128 + j] = a;
    }
    __syncthreads();
    if (t < 128) s_heads[t] = s_red[t] + s_red[128 + t] + s_red[256 + t] + s_red[384 + t];
    __syncthreads();
    {   // glimpse[d] = sum_j heads[j] Wo[j,d]
        const int d = t & 127, p = t >> 7;
        float a = 0.f;
        for (int j = 32 * p; j < 32 * p + 32; ++j)
            a = fmaf(s_heads[j], Wo[j * DD + d], a);
        s_red[p * 128 + d] = a;
    }
    __syncthreads();
    if (t < 128) s_gl[t] = s_red[t] + s_red[128 + t] + s_red[256 + t] + s_red[384 + t];
    __syncthreads();
    {   // g2[i] = (1/sqrt(128)) sum_d Wl[i,d] glimpse[d]
        const int i = t & 127, p = t >> 7;
        float a = 0.f;
        for (int d = 32 * p; d < 32 * p + 32; ++d)
            a = fmaf(Wn[i * 384 + 256 + d], s_gl[d], a);
        s_red[p * 128 + i] = a;
    }
    __syncthreads();
    if (t < 128)
        g2v[(size_t)b * 128 + t] =
            (s_red[t] + s_red[128 + t] + s_red[256 + t] + s_red[384 + t]) * 0.08838834764831845f;
}

// ---------------- K4b: logits, coalesced 4-rows-x-16-lanes ----------------
__global__ __launch_bounds__(512, 2)
void k4b_logits(const float* __restrict__ emb, const float* __restrict__ g2v,
                const void* __restrict__ maskp, const int* __restrict__ mflag,
                float* __restrict__ logits) {
    const int b = blockIdx.x >> 3, s = blockIdx.x & 7;
    const int t = threadIdx.x, w = t >> 6, lane = t & 63;
    const int rg = lane >> 4, cl = lane & 15;
    const float* eb = emb + (size_t)b * (NN * DD);
    __shared__ __align__(16) float s_g2[128];
    if (t < 128) s_g2[t] = g2v[(size_t)b * 128 + t];
    __syncthreads();
    const float4 ga = *(const float4*)&s_g2[cl * 8];
    const float4 gb = *(const float4*)&s_g2[cl * 8 + 4];
    const int use32 = *mflag;
    const unsigned char* mk8 = (const unsigned char*)maskp + (size_t)b * NN;
    const int* mk32 = (const int*)maskp + (size_t)b * NN;
    #pragma unroll
    for (int it = 0; it < 4; ++it) {
        const int r = w * 16 + it * 4 + rg;
        const int n = s * 125 + r;
        float a = 0.f;
        if (r < 125) {
            const float4 e0 = *(const float4*)(eb + (size_t)n * DD + cl * 8);
            const float4 e1 = *(const float4*)(eb + (size_t)n * DD + cl * 8 + 4);
            a = e0.x * ga.x;
            a = fmaf(e0.y, ga.y, a);
            a = fmaf(e0.z, ga.z, a);
            a = fmaf(e0.w, ga.w, a);
            a = fmaf(e1.x, gb.x, a);
            a = fmaf(e1.y, gb.y, a);
            a = fmaf(e1.z, gb.z, a);
            a = fmaf(e1.w, gb.w, a);
        }
        a += __shfl_xor(a, 1, 16);
        a += __shfl_xor(a, 2, 16);
        a += __shfl_xor(a, 4, 16);
        a += __shfl_xor(a, 8, 16);
        if (cl == 0 && r < 125) {
            const bool m = use32 ? (mk32[n] != 0) : (mk8[n] != 0);
            logits[(size_t)b * 1024 + n] = m ? NEG_BIG : 10.0f * tanhf(a);
        }
    }
}

// ---------------- K5: per-batch log_softmax ----------------
__global__ __launch_bounds__(512, 4)
void k5_logsoftmax(const float* __restrict__ logits, float* __restrict__ out) {
    const int b = blockIdx.x, t = threadIdx.x, w = t >> 6, lane = t & 63;
    __shared__ float s_red[16];
    __shared__ float s_lse;
    const float* lg = logits + (size_t)b * 1024;
    float m = NEG_BIG;
    for (int n = t; n < NN; n += 512) m = fmaxf(m, lg[n]);
    #pragma unroll
    for (int o = 32; o; o >>= 1) m = fmaxf(m, __shfl_xor(m, o, 64));
    if (lane == 0) s_red[w] = m;
    __syncthreads();
    if (t == 0) {
        float mm = s_red[0];
        #pragma unroll
        for (int i = 1; i < 8; ++i) mm = fmaxf(mm, s_red[i]);
        s_red[8] = mm;
    }
    __syncthreads();
    const float mb = s_red[8];
    float sum = 0.f;
    for (int n = t; n < NN; n += 512) sum += expf(lg[n] - mb);
    #pragma unroll
    for (int o = 32; o; o >>= 1) sum += __shfl_xor(sum, o, 64);
    __syncthreads();
    if (lane == 0) s_red[w] = sum;
    __syncthreads();
    if (t == 0) {
        float ss = 0.f;
        #pragma unroll
        for (int i = 0; i < 8; ++i) ss += s_red[i];
        s_lse = mb + logf(ss);
    }
    __syncthreads();
    const float lse = s_lse;
    float* ob = out + (size_t)b * NN;
    for (int n = t; n < NN; n += 512) ob[n] = lg[n] - lse;
}

// ============================================================================
// Fallback: round-2 fused kernel (proven), used only if ws too small.
// ============================================================================
__global__ __launch_bounds__(512, 2)
void attn_model_fused(const float* __restrict__ emb, const float* __restrict__ stepc,
                      const void* __restrict__ maskp,
                      const float* __restrict__ Wn, const float* __restrict__ Wf,
                      const float* __restrict__ Ws, const float* __restrict__ Wo,
                      float* __restrict__ out) {
    const int b = blockIdx.x, t = threadIdx.x, w = t >> 6, lane = t & 63;
    const float* eb = emb + (size_t)b * (NN * DD);
    __shared__ __align__(16) float s_compat[8 * 1024];
    __shared__ __align__(16) float s_attn[NN * 8];
    __shared__ __align__(16) float s_scr[4096];
    __shared__ float s_mean[DD], s_q[DD];
    __shared__ __align__(16) float s_qproj[DD * 8];
    __shared__ float s_wemb[DD * 8], s_heads[DD], s_glimpse[DD], s_g2[DD];
    __shared__ float s_logits[NN], s_m[8], s_s[8], s_red[16], s_lse;
    __shared__ int s_mask_is_int;
    if (t == 0) {
        const unsigned char* mb8 = (const unsigned char*)maskp;
        int any = 0;
        for (int k = 0; k < 64; ++k) any |= mb8[4 * k + 1];
        s_mask_is_int = (any == 0) ? 1 : 0;
    }
    __syncthreads();
    const int mask_is_int = s_mask_is_int;
    const unsigned char* mk8 = (const unsigned char*)maskp + (size_t)b * NN;
    const int* mk32 = (const int*)maskp + (size_t)b * NN;
#define MASKED(n) (mask_is_int ? (mk32[(n)] != 0) : (mk8[(n)] != 0))
    {
        const int c4 = t & 31, r0 = t >> 5;
        float4 a = make_float4(0.f, 0.f, 0.f, 0.f);
        for (int n = r0; n < NN; n += 16) {
            const float4 v = *(const float4*)(eb + n * DD + c4 * 4);
            a.x += v.x; a.y += v.y; a.z += v.z; a.w += v.w;
        }
        ((float4*)s_scr)[r0 * 32 + c4] = a;
    }
    __syncthreads();
    if (t < DD) {
        float s = 0.f;
        #pragma unroll
        for (int g = 0; g < 16; ++g) s += s_scr[g * 128 + t];
        s_mean[t] = s * (1.0f / (float)NN);
    }
    __syncthreads();
    {
        const int d = t & 127, p = t >> 7;
        float a = 0.f;
        for (int i = 32 * p; i < 32 * p + 32; ++i) a = fmaf(s_mean[i], Wf[i * DD + d], a);
        const float* scb = stepc + (size_t)b * CTXN;
        const int c0 = 32 * p, c1 = (p == 3) ? CTXN : 32 * p + 32;
        for (int c = c0; c < c1; ++c) a = fmaf(scb[c], Ws[c * DD + d], a);
        s_scr[p * 128 + d] = a;
    }
    __syncthreads();
    if (t < DD) s_q[t] = s_scr[t] + s_scr[128 + t] + s_scr[256 + t] + s_scr[384 + t];
    __syncthreads();
    {
        const int i = t & 127, hh = t >> 7;
        #pragma unroll
        for (int u = 0; u < 2; ++u) {
            const int h = hh + 4 * u;
            float a = 0.f;
            #pragma unroll
            for (int j = 0; j < 16; ++j) a = fmaf(Wn[i * 384 + h * 16 + j], s_q[h * 16 + j], a);
            s_qproj[i * 8 + h] = a * 0.25f;
        }
    }
    __syncthreads();
    {
        float qp[16][8];
        #pragma unroll
        for (int ii = 0; ii < 16; ++ii)
            #pragma unroll
            for (int h = 0; h < 8; ++h) qp[ii][h] = s_qproj[(w * 16 + ii) * 8 + h];
        for (int nb = 0; nb < 16; ++nb) {
            const int row = nb * 64 + lane;
            float acc[8] = {0,0,0,0,0,0,0,0};
            if (row < NN) {
                #pragma unroll
                for (int j = 0; j < 4; ++j) {
                    const float4 e = *(const float4*)(eb + row * DD + w * 16 + j * 4);
                    #pragma unroll
                    for (int h = 0; h < 8; ++h) {
                        acc[h] = fmaf(e.x, qp[4 * j + 0][h], acc[h]);
                        acc[h] = fmaf(e.y, qp[4 * j + 1][h], acc[h]);
                        acc[h] = fmaf(e.z, qp[4 * j + 2][h], acc[h]);
                        acc[h] = fmaf(e.w, qp[4 * j + 3][h], acc[h]);
                    }
                }
            }
            #pragma unroll
            for (int h = 0; h < 8; ++h) s_scr[(w * 8 + h) * 64 + lane] = acc[h];
            __syncthreads();
            {
                const int h = t >> 6, l = t & 63;
                const int rr = nb * 64 + l;
                if (rr < NN) {
                    float c = 0.f;
                    #pragma unroll
                    for (int w2 = 0; w2 < 8; ++w2) c += s_scr[(w2 * 8 + h) * 64 + l];
                    s_compat[h * 1024 + rr] = MASKED(rr) ? NEG_BIG : c;
                }
            }
            __syncthreads();
        }
    }
    {
        const int h = w;
        float m = NEG_BIG;
        for (int n = lane; n < NN; n += 64) m = fmaxf(m, s_compat[h * 1024 + n]);
        #pragma unroll
        for (int s = 32; s; s >>= 1) m = fmaxf(m, __shfl_xor(m, s, 64));
        float sum = 0.f;
        for (int n = lane; n < NN; n += 64) sum += expf(s_compat[h * 1024 + n] - m);
        #pragma unroll
        for (int s = 32; s; s >>= 1) sum += __shfl_xor(sum, s, 64);
        if (lane == 0) { s_m[h] = m; s_s[h] = 1.0f / sum; }
    }
    __syncthreads();
    for (int n = t; n < NN; n += 512) {
        #pragma unroll
        for (int h = 0; h < 8; ++h) s_attn[n * 8 + h] = expf(s_compat[h * 1024 + n] - s_m[h]) * s_s[h];
    }
    __syncthreads();
    {
        float a0[8] = {0,0,0,0,0,0,0,0}, a1[8] = {0,0,0,0,0,0,0,0};
        for (int n = w; n < NN; n += 8) {
            const float2 e = *(const float2*)(eb + n * DD + 2 * lane);
            const float4 p0 = *(const float4*)(&s_attn[n * 8]);
            const float4 p1 = *(const float4*)(&s_attn[n * 8 + 4]);
            a0[0] = fmaf(e.x, p0.x, a0[0]); a1[0] = fmaf(e.y, p0.x, a1[0]);
            a0[1] = fmaf(e.x, p0.y, a0[1]); a1[1] = fmaf(e.y, p0.y, a1[1]);
            a0[2] = fmaf(e.x, p0.z, a0[2]); a1[2] = fmaf(e.y, p0.z, a1[2]);
            a0[3] = fmaf(e.x, p0.w, a0[3]); a1[3] = fmaf(e.y, p0.w, a1[3]);
            a0[4] = fmaf(e.x, p1.x, a0[4]); a1[4] = fmaf(e.y, p1.x, a1[4]);
            a0[5] = fmaf(e.x, p1.y, a0[5]); a1[5] = fmaf(e.y, p1.y, a1[5]);
            a0[6] = fmaf(e.x, p1.z, a0[6]); a1[6] = fmaf(e.y, p1.z, a1[6]);
            a0[7] = fmaf(e.x, p1.w, a0[7]); a1[7] = fmaf(e.y, p1.w, a1[7]);
        }
        #pragma unroll
        for (int h = 0; h < 8; ++h)
            *(float2*)&s_compat[(w * 8 + h) * 128 + 2 * lane] = make_float2(a0[h], a1[h]);
    }
    __syncthreads();
    {
        const int i = t & 127, h2 = t >> 7;
        #pragma unroll
        for (int u = 0; u < 2; ++u) {
            const int h = h2 + 4 * u;
            float a = 0.f;
            #pragma unroll
            for (int w2 = 0; w2 < 8; ++w2) a += s_compat[(w2 * 8 + h) * 128 + i];
            s_wemb[i * 8 + h] = a;
        }
    }
    __syncthreads();
    if (t < DD) {
        const int h = t >> 4;
        float a = 0.f;
        for (int i = 0; i < DD; ++i) a = fmaf(Wn[i * 384 + 128 + t], s_wemb[i * 8 + h], a);
        s_heads[t] = a;
    }
    __syncthreads();
    if (t < DD) {
        float a = 0.f;
        for (int j = 0; j < DD; ++j) a = fmaf(s_heads[j], Wo[j * DD + t], a);
        s_glimpse[t] = a;
    }
    __syncthreads();
    if (t < DD) {
        float a = 0.f;
        for (int d = 0; d < DD; ++d) a = fmaf(Wn[t * 384 + 256 + d], s_glimpse[d], a);
        s_g2[t] = a * 0.08838834764831845f;
    }
    __syncthreads();
    {
        float g2r[16];
        #pragma unroll
        for (int ii = 0; ii < 16; ++ii) g2r[ii] = s_g2[w * 16 + ii];
        for (int nb = 0; nb < 16; ++nb) {
            const int row = nb * 64 + lane;
            float acc = 0.f;
            if (row < NN) {
                #pragma unroll
                for (int j = 0; j < 4; ++j) {
                    const float4 e = *(const float4*)(eb + row * DD + w * 16 + j * 4);
                    acc = fmaf(e.x, g2r[4 * j + 0], acc);
                    acc = fmaf(e.y, g2r[4 * j + 1], acc);
                    acc = fmaf(e.z, g2r[4 * j + 2], acc);
                    acc = fmaf(e.w, g2r[4 * j + 3], acc);
                }
            }
            s_scr[w * 64 + lane] = acc;
            __syncthreads();
            if (t < 64) {
                const int rr = nb * 64 + t;
                if (rr < NN) {
                    float x = 0.f;
                    #pragma unroll
                    for (int w2 = 0; w2 < 8; ++w2) x += s_scr[w2 * 64 + t];
                    s_logits[rr] = MASKED(rr) ? NEG_BIG : 10.0f * tanhf(x);
                }
            }
            __syncthreads();
        }
    }
    {
        float m = NEG_BIG;
        for (int n = t; n < NN; n += 512) m = fmaxf(m, s_logits[n]);
        #pragma unroll
        for (int s = 32; s; s >>= 1) m = fmaxf(m, __shfl_xor(m, s, 64));
        if (lane == 0) s_red[w] = m;
        __syncthreads();
        if (t == 0) {
            float mm = s_red[0];
            #pragma unroll
            for (int i = 1; i < 8; ++i) mm = fmaxf(mm, s_red[i]);
            s_red[8] = mm;
        }
        __syncthreads();
        const float mb = s_red[8];
        float sum = 0.f;
        for (int n = t; n < NN; n += 512) sum += expf(s_logits[n] - mb);
        #pragma unroll
        for (int s = 32; s; s >>= 1) sum += __shfl_xor(sum, s, 64);
        __syncthreads();
        if (lane == 0) s_red[w] = sum;
        __syncthreads();
        if (t == 0) {
            float ss = 0.f;
            #pragma unroll
            for (int i = 0; i < 8; ++i) ss += s_red[i];
            s_lse = mb + logf(ss);
        }
        __syncthreads();
        const float lse = s_lse;
        float* ob = out + (size_t)b * NN;
        for (int n = t; n < NN; n += 512) ob[n] = s_logits[n] - lse;
    }
#undef MASKED
}

extern "C" void kernel_launch(void* const* d_in, const int* in_sizes, int n_in,
                              void* d_out, int out_size, void* d_ws, size_t ws_size,
                              hipStream_t stream) {
    const float* emb   = (const float*)d_in[0];
    const float* stepc = (const float*)d_in[1];
    const void*  mask  = (const void*)d_in[2];
    const float* Wn = (const float*)d_in[3];
    const float* Wf = (const float*)d_in[4];
    const float* Ws = (const float*)d_in[5];
    const float* Wo = (const float*)d_in[6];
    float* out = (float*)d_out;
    const int B = in_sizes[0] / (NN * DD);  // 256

    float* wsf = (float*)d_ws;
    const size_t n_meanp = (size_t)B * 1024;
    const size_t n_qpt   = (size_t)B * 1024;
    const size_t n_comp  = (size_t)B * 8192;
    const size_t n_wembp = (size_t)B * 8192;
    const size_t n_g2    = (size_t)B * 128;
    const size_t n_stats = (size_t)B * 16;
    const size_t n_logit = (size_t)B * 1024;
    const size_t need = (n_meanp + n_qpt + n_comp + n_wembp + n_g2 + n_stats + n_logit + 16) * sizeof(float);

    if (ws_size < need) {
        attn_model_fused<<<B, 512, 0, stream>>>(emb, stepc, mask, Wn, Wf, Ws, Wo, out);
        return;
    }
    float* meanp  = wsf;
    float* qpt    = meanp + n_meanp;
    float* compat = qpt + n_qpt;
    float* wembp  = compat + n_comp;
    float* g2v    = wembp + n_wembp;
    float* stats  = g2v + n_g2;
    float* logits = stats + n_stats;
    int*   mflag  = (int*)(logits + n_logit);

    k1_meanpart  <<<B * 8, 256, 0, stream>>>(emb, meanp);
    k1b_qproj    <<<B,     512, 0, stream>>>(meanp, stepc, mask, Wn, Wf, Ws, qpt, mflag);
    k2_compat    <<<B * 8, 512, 0, stream>>>(emb, qpt, mask, mflag, compat);
    k2b_stats    <<<B,     512, 0, stream>>>(compat, stats);
    k3_wembp     <<<B * 8, 512, 0, stream>>>(emb, compat, stats, wembp);
    k4a_g2       <<<B,     512, 0, stream>>>(wembp, Wn, Wo, g2v);
    k4b_logits   <<<B * 8, 512, 0, stream>>>(emb, g2v, mask, mflag, logits);
    k5_logsoftmax<<<B,     512, 0, stream>>>(logits, out);
}

// Round 5
// 134.032 us; speedup vs baseline: 1.6530x; 1.0490x over previous
//
#include <hip/hip_runtime.h>
#include <math.h>

#define NN   1000
#define DD   128
#define CTXN 130
#define NEG_BIG (-1.0e30f)

// ============================================================================
// Pipeline (3 HBM passes over emb; slice-local online softmax):
//  k1  (B*8): per-slice column sums                       (emb pass 1)
//  k1b (B)  : mean -> query -> qproj[h][i], mask probe
//  kB  (B*8): compat -> local max/sum -> wembp_s          (emb pass 2, x2 reads, 2nd L2-hot)
//  k4a (B)  : rescale-merge slices -> wemb -> heads -> glimpse -> g2
//  k4b (B*8): logits[n] = 10*tanh(emb_n . g2)             (emb pass 3)
//  k5  (B)  : log_softmax
// ws: meanp[B][1024] | qpt[B][1024] | wembp[B][8][1024] | g2v[B][128]
//     | stats[B][8][16] | logits[B][1024] | mflag
// ============================================================================

// ---------------- K1: per-(b,s) partial column sums ----------------
__global__ __launch_bounds__(256, 8)
void k1_meanpart(const float* __restrict__ emb, float* __restrict__ meanp) {
    const int b = blockIdx.x >> 3, s = blockIdx.x & 7;
    const int t = threadIdx.x;
    const float* eb = emb + (size_t)b * (NN * DD);
    __shared__ __align__(16) float s_red[8 * 128];
    const int c4 = t & 31, rg = t >> 5;
    float4 a = make_float4(0.f, 0.f, 0.f, 0.f);
    for (int nl = rg; nl < 125; nl += 8) {
        const float4 v = *(const float4*)(eb + (size_t)(s * 125 + nl) * DD + c4 * 4);
        a.x += v.x; a.y += v.y; a.z += v.z; a.w += v.w;
    }
    ((float4*)s_red)[rg * 32 + c4] = a;
    __syncthreads();
    if (t < 128) {
        float v = 0.f;
        #pragma unroll
        for (int g = 0; g < 8; ++g) v += s_red[g * 128 + t];
        meanp[(size_t)b * 1024 + s * 128 + t] = v;
    }
}

// ---------------- K1b: mean -> query -> qproj [h][i], + mask layout probe ----------------
__global__ __launch_bounds__(512, 4)
void k1b_qproj(const float* __restrict__ meanp, const float* __restrict__ stepc,
               const void* __restrict__ maskp,
               const float* __restrict__ Wn, const float* __restrict__ Wf,
               const float* __restrict__ Ws,
               float* __restrict__ qpt, int* __restrict__ mflag) {
    const int b = blockIdx.x, t = threadIdx.x;
    __shared__ float s_mean[128], s_q[128];
    __shared__ float s_red[512];
    if (b == 0 && t == 0) {   // int32 mask: bytes at 1 mod 4 are always 0
        const unsigned char* mb8 = (const unsigned char*)maskp;
        int any = 0;
        for (int k = 0; k < 64; ++k) any |= mb8[4 * k + 1];
        *mflag = (any == 0) ? 1 : 0;
    }
    if (t < 128) {
        float v = 0.f;
        #pragma unroll
        for (int g = 0; g < 8; ++g) v += meanp[(size_t)b * 1024 + g * 128 + t];
        s_mean[t] = v * (1.0f / (float)NN);
    }
    __syncthreads();
    {   // query[d] = sum_i mean[i] Wf[i,d] + sum_c sc[c] Ws[c,d]
        const int d = t & 127, p = t >> 7;
        float a = 0.f;
        for (int i = 32 * p; i < 32 * p + 32; ++i)
            a = fmaf(s_mean[i], Wf[i * DD + d], a);
        const float* scb = stepc + (size_t)b * CTXN;
        const int c0 = 32 * p, c1 = (p == 3) ? CTXN : 32 * p + 32;
        for (int c = c0; c < c1; ++c)
            a = fmaf(scb[c], Ws[c * DD + d], a);
        s_red[p * 128 + d] = a;
    }
    __syncthreads();
    if (t < 128) s_q[t] = s_red[t] + s_red[128 + t] + s_red[256 + t] + s_red[384 + t];
    __syncthreads();
    {   // qpt[b][h][i] = 0.25 * sum_j Wn[i, 16h+j] q[16h+j]
        const int i = t & 127, p = t >> 7;
        #pragma unroll
        for (int u = 0; u < 2; ++u) {
            const int h = p + 4 * u;
            float a = 0.f;
            #pragma unroll
            for (int j = 0; j < 16; ++j)
                a = fmaf(Wn[i * 384 + h * 16 + j], s_q[h * 16 + j], a);
            qpt[(size_t)b * 1024 + h * 128 + i] = a * 0.25f;
        }
    }
}

// ---------------- KB: fused compat + slice-local softmax + wembp ----------------
// step1: compat[r][h] (4-rows-x-16-lanes, coalesced); step2: local m/sum per head;
// step3: p = exp(compat - m_loc); step4: wembp_s[i][h] = sum_r p[r][h] emb[r][i]
// (2nd emb read is L2/L3-hot). Fully-masked slices self-zero at merge via
// exp(m_s - m_glob) = exp(-1e30...) = 0.
__global__ __launch_bounds__(512, 2)
void kB_fused(const float* __restrict__ emb, const float* __restrict__ qpt,
              const void* __restrict__ maskp, const int* __restrict__ mflag,
              float* __restrict__ wembp, float* __restrict__ stats) {
    const int b = blockIdx.x >> 3, s = blockIdx.x & 7;
    const int t = threadIdx.x, w = t >> 6, lane = t & 63;
    const int rg = lane >> 4, cl = lane & 15;
    const float* eb = emb + (size_t)b * (NN * DD);
    __shared__ __align__(16) float s_qpT[1024];
    __shared__ __align__(16) float s_compat[128 * 8];  // [r][h]
    __shared__ __align__(16) float s_p[128 * 8];       // [r][h] unnormalized
    __shared__ float s_m[8], s_sum[8];
    __shared__ float s_part[8 * 8 * 132];              // [w][h][132]
    for (int i = t; i < 1024; i += 512) s_qpT[i] = qpt[(size_t)b * 1024 + i];
    __syncthreads();
    float4 qa[8], qb[8];   // qproj cols cl*8..cl*8+7 for all 8 heads
    #pragma unroll
    for (int h = 0; h < 8; ++h) {
        qa[h] = *(const float4*)&s_qpT[h * 128 + cl * 8];
        qb[h] = *(const float4*)&s_qpT[h * 128 + cl * 8 + 4];
    }
    const int use32 = *mflag;
    const unsigned char* mk8 = (const unsigned char*)maskp + (size_t)b * NN;
    const int* mk32 = (const int*)maskp + (size_t)b * NN;
    // ---- step 1: compat into LDS ----
    #pragma unroll
    for (int it = 0; it < 4; ++it) {
        const int r = w * 16 + it * 4 + rg;     // 0..127
        const int n = s * 125 + r;
        float acc[8] = {0.f,0.f,0.f,0.f,0.f,0.f,0.f,0.f};
        if (r < 125) {
            const float4 e0 = *(const float4*)(eb + (size_t)n * DD + cl * 8);
            const float4 e1 = *(const float4*)(eb + (size_t)n * DD + cl * 8 + 4);
            #pragma unroll
            for (int h = 0; h < 8; ++h) {
                float a = e0.x * qa[h].x;
                a = fmaf(e0.y, qa[h].y, a);
                a = fmaf(e0.z, qa[h].z, a);
                a = fmaf(e0.w, qa[h].w, a);
                a = fmaf(e1.x, qb[h].x, a);
                a = fmaf(e1.y, qb[h].y, a);
                a = fmaf(e1.z, qb[h].z, a);
                a = fmaf(e1.w, qb[h].w, a);
                acc[h] = a;
            }
        }
        #pragma unroll
        for (int h = 0; h < 8; ++h) {
            acc[h] += __shfl_xor(acc[h], 1, 16);
            acc[h] += __shfl_xor(acc[h], 2, 16);
            acc[h] += __shfl_xor(acc[h], 4, 16);
            acc[h] += __shfl_xor(acc[h], 8, 16);
        }
        if (cl == 0 && r < 125) {
            const bool m = use32 ? (mk32[n] != 0) : (mk8[n] != 0);
            float4 o0, o1;
            if (m) { o0 = make_float4(NEG_BIG, NEG_BIG, NEG_BIG, NEG_BIG); o1 = o0; }
            else   { o0 = make_float4(acc[0], acc[1], acc[2], acc[3]);
                     o1 = make_float4(acc[4], acc[5], acc[6], acc[7]); }
            *(float4*)&s_compat[r * 8]     = o0;
            *(float4*)&s_compat[r * 8 + 4] = o1;
        }
    }
    __syncthreads();
    // ---- step 2: local per-head max / raw sum (wave w = head w) ----
    {
        float m = NEG_BIG;
        for (int r = lane; r < 125; r += 64) m = fmaxf(m, s_compat[r * 8 + w]);
        #pragma unroll
        for (int o = 32; o; o >>= 1) m = fmaxf(m, __shfl_xor(m, o, 64));
        float sum = 0.f;
        for (int r = lane; r < 125; r += 64) sum += expf(s_compat[r * 8 + w] - m);
        #pragma unroll
        for (int o = 32; o; o >>= 1) sum += __shfl_xor(sum, o, 64);
        if (lane == 0) { s_m[w] = m; s_sum[w] = sum; }
    }
    __syncthreads();
    // ---- step 3: unnormalized p ----
    for (int idx = t; idx < 1000; idx += 512)
        s_p[idx] = expf(s_compat[idx] - s_m[idx & 7]);
    __syncthreads();
    // ---- step 4: wembp_s[i][h] (2nd emb read, L2-hot) ----
    {
        float a0[8] = {0,0,0,0,0,0,0,0}, a1[8] = {0,0,0,0,0,0,0,0};
        for (int nl = w; nl < 125; nl += 8) {
            const float2 e  = *(const float2*)(eb + (size_t)(s * 125 + nl) * DD + 2 * lane);
            const float4 p0 = *(const float4*)&s_p[nl * 8];
            const float4 p1 = *(const float4*)&s_p[nl * 8 + 4];
            a0[0] = fmaf(e.x, p0.x, a0[0]); a1[0] = fmaf(e.y, p0.x, a1[0]);
            a0[1] = fmaf(e.x, p0.y, a0[1]); a1[1] = fmaf(e.y, p0.y, a1[1]);
            a0[2] = fmaf(e.x, p0.z, a0[2]); a1[2] = fmaf(e.y, p0.z, a1[2]);
            a0[3] = fmaf(e.x, p0.w, a0[3]); a1[3] = fmaf(e.y, p0.w, a1[3]);
            a0[4] = fmaf(e.x, p1.x, a0[4]); a1[4] = fmaf(e.y, p1.x, a1[4]);
            a0[5] = fmaf(e.x, p1.y, a0[5]); a1[5] = fmaf(e.y, p1.y, a1[5]);
            a0[6] = fmaf(e.x, p1.z, a0[6]); a1[6] = fmaf(e.y, p1.z, a1[6]);
            a0[7] = fmaf(e.x, p1.w, a0[7]); a1[7] = fmaf(e.y, p1.w, a1[7]);
        }
        #pragma unroll
        for (int h = 0; h < 8; ++h)
            *(float2*)&s_part[(w * 8 + h) * 132 + 2 * lane] = make_float2(a0[h], a1[h]);
    }
    __syncthreads();
    for (int idx = t; idx < 1024; idx += 512) {
        const int h = idx >> 7, i = idx & 127;
        float v = 0.f;
        #pragma unroll
        for (int g = 0; g < 8; ++g) v += s_part[(g * 8 + h) * 132 + i];
        wembp[(size_t)b * 8192 + s * 1024 + idx] = v;   // [b][s][h][i]
    }
    if (t < 8)        stats[(size_t)b * 128 + s * 16 + t] = s_m[t];
    else if (t < 16)  stats[(size_t)b * 128 + s * 16 + t] = s_sum[t - 8];
}

// ---------------- K4a: rescale-merge -> wemb -> heads -> glimpse -> g2 ----------------
__global__ __launch_bounds__(512, 4)
void k4a_g2(const float* __restrict__ wembp, const float* __restrict__ stats,
            const float* __restrict__ Wn, const float* __restrict__ Wo,
            float* __restrict__ g2v) {
    const int b = blockIdx.x, t = threadIdx.x;
    __shared__ float s_w[8][8];         // [s][h] merge weight
    __shared__ float s_wemb[8 * 130];   // [h][130]
    __shared__ float s_red[512];
    __shared__ float s_heads[128], s_gl[128];
    if (t < 8) {   // per-head global max/denominator + per-slice weights
        const int h = t;
        float m = NEG_BIG;
        #pragma unroll
        for (int s = 0; s < 8; ++s) m = fmaxf(m, stats[(size_t)b * 128 + s * 16 + h]);
        float den = 0.f;
        #pragma unroll
        for (int s = 0; s < 8; ++s)
            den += stats[(size_t)b * 128 + s * 16 + 8 + h] * expf(stats[(size_t)b * 128 + s * 16 + h] - m);
        const float dinv = 1.0f / den;
        #pragma unroll
        for (int s = 0; s < 8; ++s)
            s_w[s][h] = expf(stats[(size_t)b * 128 + s * 16 + h] - m) * dinv;
    }
    __syncthreads();
    for (int idx = t; idx < 1024; idx += 512) {
        const int h = idx >> 7, i = idx & 127;
        float v = 0.f;
        #pragma unroll
        for (int s = 0; s < 8; ++s) v += wembp[(size_t)b * 8192 + s * 1024 + idx] * s_w[s][h];
        s_wemb[h * 130 + i] = v;
    }
    __syncthreads();
    {   // heads[j] = sum_i Wv[i,j] wemb[j>>4][i]
        const int j = t & 127, p = t >> 7;
        float a = 0.f;
        for (int i = 32 * p; i < 32 * p + 32; ++i)
            a = fmaf(Wn[i * 384 + 128 + j], s_wemb[(j >> 4) * 130 + i], a);
        s_red[p * 128 + j] = a;
    }
    __syncthreads();
    if (t < 128) s_heads[t] = s_red[t] + s_red[128 + t] + s_red[256 + t] + s_red[384 + t];
    __syncthreads();
    {   // glimpse[d] = sum_j heads[j] Wo[j,d]
        const int d = t & 127, p = t >> 7;
        float a = 0.f;
        for (int j = 32 * p; j < 32 * p + 32; ++j)
            a = fmaf(s_heads[j], Wo[j * DD + d], a);
        s_red[p * 128 + d] = a;
    }
    __syncthreads();
    if (t < 128) s_gl[t] = s_red[t] + s_red[128 + t] + s_red[256 + t] + s_red[384 + t];
    __syncthreads();
    {   // g2[i] = (1/sqrt(128)) sum_d Wl[i,d] glimpse[d]
        const int i = t & 127, p = t >> 7;
        float a = 0.f;
        for (int d = 32 * p; d < 32 * p + 32; ++d)
            a = fmaf(Wn[i * 384 + 256 + d], s_gl[d], a);
        s_red[p * 128 + i] = a;
    }
    __syncthreads();
    if (t < 128)
        g2v[(size_t)b * 128 + t] =
            (s_red[t] + s_red[128 + t] + s_red[256 + t] + s_red[384 + t]) * 0.08838834764831845f;
}

// ---------------- K4b: logits, coalesced 4-rows-x-16-lanes ----------------
__global__ __launch_bounds__(512, 2)
void k4b_logits(const float* __restrict__ emb, const float* __restrict__ g2v,
                const void* __restrict__ maskp, const int* __restrict__ mflag,
                float* __restrict__ logits) {
    const int b = blockIdx.x >> 3, s = blockIdx.x & 7;
    const int t = threadIdx.x, w = t >> 6, lane = t & 63;
    const int rg = lane >> 4, cl = lane & 15;
    const float* eb = emb + (size_t)b * (NN * DD);
    __shared__ __align__(16) float s_g2[128];
    if (t < 128) s_g2[t] = g2v[(size_t)b * 128 + t];
    __syncthreads();
    const float4 ga = *(const float4*)&s_g2[cl * 8];
    const float4 gb = *(const float4*)&s_g2[cl * 8 + 4];
    const int use32 = *mflag;
    const unsigned char* mk8 = (const unsigned char*)maskp + (size_t)b * NN;
    const int* mk32 = (const int*)maskp + (size_t)b * NN;
    #pragma unroll
    for (int it = 0; it < 4; ++it) {
        const int r = w * 16 + it * 4 + rg;
        const int n = s * 125 + r;
        float a = 0.f;
        if (r < 125) {
            const float4 e0 = *(const float4*)(eb + (size_t)n * DD + cl * 8);
            const float4 e1 = *(const float4*)(eb + (size_t)n * DD + cl * 8 + 4);
            a = e0.x * ga.x;
            a = fmaf(e0.y, ga.y, a);
            a = fmaf(e0.z, ga.z, a);
            a = fmaf(e0.w, ga.w, a);
            a = fmaf(e1.x, gb.x, a);
            a = fmaf(e1.y, gb.y, a);
            a = fmaf(e1.z, gb.z, a);
            a = fmaf(e1.w, gb.w, a);
        }
        a += __shfl_xor(a, 1, 16);
        a += __shfl_xor(a, 2, 16);
        a += __shfl_xor(a, 4, 16);
        a += __shfl_xor(a, 8, 16);
        if (cl == 0 && r < 125) {
            const bool m = use32 ? (mk32[n] != 0) : (mk8[n] != 0);
            logits[(size_t)b * 1024 + n] = m ? NEG_BIG : 10.0f * tanhf(a);
        }
    }
}

// ---------------- K5: per-batch log_softmax ----------------
__global__ __launch_bounds__(512, 4)
void k5_logsoftmax(const float* __restrict__ logits, float* __restrict__ out) {
    const int b = blockIdx.x, t = threadIdx.x, w = t >> 6, lane = t & 63;
    __shared__ float s_red[16];
    __shared__ float s_lse;
    const float* lg = logits + (size_t)b * 1024;
    float m = NEG_BIG;
    for (int n = t; n < NN; n += 512) m = fmaxf(m, lg[n]);
    #pragma unroll
    for (int o = 32; o; o >>= 1) m = fmaxf(m, __shfl_xor(m, o, 64));
    if (lane == 0) s_red[w] = m;
    __syncthreads();
    if (t == 0) {
        float mm = s_red[0];
        #pragma unroll
        for (int i = 1; i < 8; ++i) mm = fmaxf(mm, s_red[i]);
        s_red[8] = mm;
    }
    __syncthreads();
    const float mb = s_red[8];
    float sum = 0.f;
    for (int n = t; n < NN; n += 512) sum += expf(lg[n] - mb);
    #pragma unroll
    for (int o = 32; o; o >>= 1) sum += __shfl_xor(sum, o, 64);
    __syncthreads();
    if (lane == 0) s_red[w] = sum;
    __syncthreads();
    if (t == 0) {
        float ss = 0.f;
        #pragma unroll
        for (int i = 0; i < 8; ++i) ss += s_red[i];
        s_lse = mb + logf(ss);
    }
    __syncthreads();
    const float lse = s_lse;
    float* ob = out + (size_t)b * NN;
    for (int n = t; n < NN; n += 512) ob[n] = lg[n] - lse;
}

// ============================================================================
// Fallback: round-2 fused kernel (proven), used only if ws too small.
// ============================================================================
__global__ __launch_bounds__(512, 2)
void attn_model_fused(const float* __restrict__ emb, const float* __restrict__ stepc,
                      const void* __restrict__ maskp,
                      const float* __restrict__ Wn, const float* __restrict__ Wf,
                      const float* __restrict__ Ws, const float* __restrict__ Wo,
                      float* __restrict__ out) {
    const int b = blockIdx.x, t = threadIdx.x, w = t >> 6, lane = t & 63;
    const float* eb = emb + (size_t)b * (NN * DD);
    __shared__ __align__(16) float s_compat[8 * 1024];
    __shared__ __align__(16) float s_attn[NN * 8];
    __shared__ __align__(16) float s_scr[4096];
    __shared__ float s_mean[DD], s_q[DD];
    __shared__ __align__(16) float s_qproj[DD * 8];
    __shared__ float s_wemb[DD * 8], s_heads[DD], s_glimpse[DD], s_g2[DD];
    __shared__ float s_logits[NN], s_m[8], s_s[8], s_red[16], s_lse;
    __shared__ int s_mask_is_int;
    if (t == 0) {
        const unsigned char* mb8 = (const unsigned char*)maskp;
        int any = 0;
        for (int k = 0; k < 64; ++k) any |= mb8[4 * k + 1];
        s_mask_is_int = (any == 0) ? 1 : 0;
    }
    __syncthreads();
    const int mask_is_int = s_mask_is_int;
    const unsigned char* mk8 = (const unsigned char*)maskp + (size_t)b * NN;
    const int* mk32 = (const int*)maskp + (size_t)b * NN;
#define MASKED(n) (mask_is_int ? (mk32[(n)] != 0) : (mk8[(n)] != 0))
    {
        const int c4 = t & 31, r0 = t >> 5;
        float4 a = make_float4(0.f, 0.f, 0.f, 0.f);
        for (int n = r0; n < NN; n += 16) {
            const float4 v = *(const float4*)(eb + n * DD + c4 * 4);
            a.x += v.x; a.y += v.y; a.z += v.z; a.w += v.w;
        }
        ((float4*)s_scr)[r0 * 32 + c4] = a;
    }
    __syncthreads();
    if (t < DD) {
        float s = 0.f;
        #pragma unroll
        for (int g = 0; g < 16; ++g) s += s_scr[g * 128 + t];
        s_mean[t] = s * (1.0f / (float)NN);
    }
    __syncthreads();
    {
        const int d = t & 127, p = t >> 7;
        float a = 0.f;
        for (int i = 32 * p; i < 32 * p + 32; ++i) a = fmaf(s_mean[i], Wf[i * DD + d], a);
        const float* scb = stepc + (size_t)b * CTXN;
        const int c0 = 32 * p, c1 = (p == 3) ? CTXN : 32 * p + 32;
        for (int c = c0; c < c1; ++c) a = fmaf(scb[c], Ws[c * DD + d], a);
        s_scr[p * 128 + d] = a;
    }
    __syncthreads();
    if (t < DD) s_q[t] = s_scr[t] + s_scr[128 + t] + s_scr[256 + t] + s_scr[384 + t];
    __syncthreads();
    {
        const int i = t & 127, hh = t >> 7;
        #pragma unroll
        for (int u = 0; u < 2; ++u) {
            const int h = hh + 4 * u;
            float a = 0.f;
            #pragma unroll
            for (int j = 0; j < 16; ++j) a = fmaf(Wn[i * 384 + h * 16 + j], s_q[h * 16 + j], a);
            s_qproj[i * 8 + h] = a * 0.25f;
        }
    }
    __syncthreads();
    {
        float qp[16][8];
        #pragma unroll
        for (int ii = 0; ii < 16; ++ii)
            #pragma unroll
            for (int h = 0; h < 8; ++h) qp[ii][h] = s_qproj[(w * 16 + ii) * 8 + h];
        for (int nb = 0; nb < 16; ++nb) {
            const int row = nb * 64 + lane;
            float acc[8] = {0,0,0,0,0,0,0,0};
            if (row < NN) {
                #pragma unroll
                for (int j = 0; j < 4; ++j) {
                    const float4 e = *(const float4*)(eb + row * DD + w * 16 + j * 4);
                    #pragma unroll
                    for (int h = 0; h < 8; ++h) {
                        acc[h] = fmaf(e.x, qp[4 * j + 0][h], acc[h]);
                        acc[h] = fmaf(e.y, qp[4 * j + 1][h], acc[h]);
                        acc[h] = fmaf(e.z, qp[4 * j + 2][h], acc[h]);
                        acc[h] = fmaf(e.w, qp[4 * j + 3][h], acc[h]);
                    }
                }
            }
            #pragma unroll
            for (int h = 0; h < 8; ++h) s_scr[(w * 8 + h) * 64 + lane] = acc[h];
            __syncthreads();
            {
                const int h = t >> 6, l = t & 63;
                const int rr = nb * 64 + l;
                if (rr < NN) {
                    float c = 0.f;
                    #pragma unroll
                    for (int w2 = 0; w2 < 8; ++w2) c += s_scr[(w2 * 8 + h) * 64 + l];
                    s_compat[h * 1024 + rr] = MASKED(rr) ? NEG_BIG : c;
                }
            }
            __syncthreads();
        }
    }
    {
        const int h = w;
        float m = NEG_BIG;
        for (int n = lane; n < NN; n += 64) m = fmaxf(m, s_compat[h * 1024 + n]);
        #pragma unroll
        for (int s = 32; s; s >>= 1) m = fmaxf(m, __shfl_xor(m, s, 64));
        float sum = 0.f;
        for (int n = lane; n < NN; n += 64) sum += expf(s_compat[h * 1024 + n] - m);
        #pragma unroll
        for (int s = 32; s; s >>= 1) sum += __shfl_xor(sum, s, 64);
        if (lane == 0) { s_m[h] = m; s_s[h] = 1.0f / sum; }
    }
    __syncthreads();
    for (int n = t; n < NN; n += 512) {
        #pragma unroll
        for (int h = 0; h < 8; ++h) s_attn[n * 8 + h] = expf(s_compat[h * 1024 + n] - s_m[h]) * s_s[h];
    }
    __syncthreads();
    {
        float a0[8] = {0,0,0,0,0,0,0,0}, a1[8] = {0,0,0,0,0,0,0,0};
        for (int n = w; n < NN; n += 8) {
            const float2 e = *(const float2*)(eb + n * DD + 2 * lane);
            const float4 p0 = *(const float4*)(&s_attn[n * 8]);
            const float4 p1 = *(const float4*)(&s_attn[n * 8 + 4]);
            a0[0] = fmaf(e.x, p0.x, a0[0]); a1[0] = fmaf(e.y, p0.x, a1[0]);
            a0[1] = fmaf(e.x, p0.y, a0[1]); a1[1] = fmaf(e.y, p0.y, a1[1]);
            a0[2] = fmaf(e.x, p0.z, a0[2]); a1[2] = fmaf(e.y, p0.z, a1[2]);
            a0[3] = fmaf(e.x, p0.w, a0[3]); a1[3] = fmaf(e.y, p0.w, a1[3]);
            a0[4] = fmaf(e.x, p1.x, a0[4]); a1[4] = fmaf(e.y, p1.x, a1[4]);
            a0[5] = fmaf(e.x, p1.y, a0[5]); a1[5] = fmaf(e.y, p1.y, a1[5]);
            a0[6] = fmaf(e.x, p1.z, a0[6]); a1[6] = fmaf(e.y, p1.z, a1[6]);
            a0[7] = fmaf(e.x, p1.w, a0[7]); a1[7] = fmaf(e.y, p1.w, a1[7]);
        }
        #pragma unroll
        for (int h = 0; h < 8; ++h)
            *(float2*)&s_compat[(w * 8 + h) * 128 + 2 * lane] = make_float2(a0[h], a1[h]);
    }
    __syncthreads();
    {
        const int i = t & 127, h2 = t >> 7;
        #pragma unroll
        for (int u = 0; u < 2; ++u) {
            const int h = h2 + 4 * u;
            float a = 0.f;
            #pragma unroll
            for (int w2 = 0; w2 < 8; ++w2) a += s_compat[(w2 * 8 + h) * 128 + i];
            s_wemb[i * 8 + h] = a;
        }
    }
    __syncthreads();
    if (t < DD) {
        const int h = t >> 4;
        float a = 0.f;
        for (int i = 0; i < DD; ++i) a = fmaf(Wn[i * 384 + 128 + t], s_wemb[i * 8 + h], a);
        s_heads[t] = a;
    }
    __syncthreads();
    if (t < DD) {
        float a = 0.f;
        for (int j = 0; j < DD; ++j) a = fmaf(s_heads[j], Wo[j * DD + t], a);
        s_glimpse[t] = a;
    }
    __syncthreads();
    if (t < DD) {
        float a = 0.f;
        for (int d = 0; d < DD; ++d) a = fmaf(Wn[t * 384 + 256 + d], s_glimpse[d], a);
        s_g2[t] = a * 0.08838834764831845f;
    }
    __syncthreads();
    {
        float g2r[16];
        #pragma unroll
        for (int ii = 0; ii < 16; ++ii) g2r[ii] = s_g2[w * 16 + ii];
        for (int nb = 0; nb < 16; ++nb) {
            const int row = nb * 64 + lane;
            float acc = 0.f;
            if (row < NN) {
                #pragma unroll
                for (int j = 0; j < 4; ++j) {
                    const float4 e = *(const float4*)(eb + row * DD + w * 16 + j * 4);
                    acc = fmaf(e.x, g2r[4 * j + 0], acc);
                    acc = fmaf(e.y, g2r[4 * j + 1], acc);
                    acc = fmaf(e.z, g2r[4 * j + 2], acc);
                    acc = fmaf(e.w, g2r[4 * j + 3], acc);
                }
            }
            s_scr[w * 64 + lane] = acc;
            __syncthreads();
            if (t < 64) {
                const int rr = nb * 64 + t;
                if (rr < NN) {
                    float x = 0.f;
                    #pragma unroll
                    for (int w2 = 0; w2 < 8; ++w2) x += s_scr[w2 * 64 + t];
                    s_logits[rr] = MASKED(rr) ? NEG_BIG : 10.0f * tanhf(x);
                }
            }
            __syncthreads();
        }
    }
    {
        float m = NEG_BIG;
        for (int n = t; n < NN; n += 512) m = fmaxf(m, s_logits[n]);
        #pragma unroll
        for (int s = 32; s; s >>= 1) m = fmaxf(m, __shfl_xor(m, s, 64));
        if (lane == 0) s_red[w] = m;
        __syncthreads();
        if (t == 0) {
            float mm = s_red[0];
            #pragma unroll
            for (int i = 1; i < 8; ++i) mm = fmaxf(mm, s_red[i]);
            s_red[8] = mm;
        }
        __syncthreads();
        const float mb = s_red[8];
        float sum = 0.f;
        for (int n = t; n < NN; n += 512) sum += expf(s_logits[n] - mb);
        #pragma unroll
        for (int s = 32; s; s >>= 1) sum += __shfl_xor(sum, s, 64);
        __syncthreads();
        if (lane == 0) s_red[w] = sum;
        __syncthreads();
        if (t == 0) {
            float ss = 0.f;
            #pragma unroll
            for (int i = 0; i < 8; ++i) ss += s_red[i];
            s_lse = mb + logf(ss);
        }
        __syncthreads();
        const float lse = s_lse;
        float* ob = out + (size_t)b * NN;
        for (int n = t; n < NN; n += 512) ob[n] = s_logits[n] - lse;
    }
#undef MASKED
}

extern "C" void kernel_launch(void* const* d_in, const int* in_sizes, int n_in,
                              void* d_out, int out_size, void* d_ws, size_t ws_size,
                              hipStream_t stream) {
    const float* emb   = (const float*)d_in[0];
    const float* stepc = (const float*)d_in[1];
    const void*  mask  = (const void*)d_in[2];
    const float* Wn = (const float*)d_in[3];
    const float* Wf = (const float*)d_in[4];
    const float* Ws = (const float*)d_in[5];
    const float* Wo = (const float*)d_in[6];
    float* out = (float*)d_out;
    const int B = in_sizes[0] / (NN * DD);  // 256

    float* wsf = (float*)d_ws;
    const size_t n_meanp = (size_t)B * 1024;
    const size_t n_qpt   = (size_t)B * 1024;
    const size_t n_wembp = (size_t)B * 8192;
    const size_t n_g2    = (size_t)B * 128;
    const size_t n_stats = (size_t)B * 128;
    const size_t n_logit = (size_t)B * 1024;
    const size_t need = (n_meanp + n_qpt + n_wembp + n_g2 + n_stats + n_logit + 16) * sizeof(float);

    if (ws_size < need) {
        attn_model_fused<<<B, 512, 0, stream>>>(emb, stepc, mask, Wn, Wf, Ws, Wo, out);
        return;
    }
    float* meanp  = wsf;
    float* qpt    = meanp + n_meanp;
    float* wembp  = qpt + n_qpt;
    float* g2v    = wembp + n_wembp;
    float* stats  = g2v + n_g2;
    float* logits = stats + n_stats;
    int*   mflag  = (int*)(logits + n_logit);

    k1_meanpart  <<<B * 8, 256, 0, stream>>>(emb, meanp);
    k1b_qproj    <<<B,     512, 0, stream>>>(meanp, stepc, mask, Wn, Wf, Ws, qpt, mflag);
    kB_fused     <<<B * 8, 512, 0, stream>>>(emb, qpt, mask, mflag, wembp, stats);
    k4a_g2       <<<B,     512, 0, stream>>>(wembp, stats, Wn, Wo, g2v);
    k4b_logits   <<<B * 8, 512, 0, stream>>>(emb, g2v, mask, mflag, logits);
    k5_logsoftmax<<<B,     512, 0, stream>>>(logits, out);
}